// Round 4
// baseline (100.577 us; speedup 1.0000x reference)
//
#include <hip/hip_runtime.h>

#define BATCH 4
#define SEQ   2048
#define EMB   128
#define NH    16
#define DK    8

// log2(e) / sqrt(8): fold softmax temperature into exp2 (pre-multiplied into qf)
#define QSCALE 0.510069726f

typedef _Float16 v4h  __attribute__((ext_vector_type(4)));
typedef _Float16 v8h  __attribute__((ext_vector_type(8)));
typedef __fp16   v2fp __attribute__((ext_vector_type(2)));
typedef float    v4f  __attribute__((ext_vector_type(4)));
typedef float    v16f __attribute__((ext_vector_type(16)));

// ---------------------------------------------------------------------------
// R19: phase-free attention. R16 (2x waves) / R17 (exp offload) / R18 (S-skew)
// all flat/negative => not occupancy-, trans-, or per-wave-ILP-bound. The one
// untouched structural suspect: the chunk phase structure (barrier -> staging
// [trans+LDS-heavy, VALU-idle] -> barrier -> compute) convoys all waves on a
// CU and segregates pipe usage in time, leaving ~45% of issue slots empty.
// Fix: feat_kernel materializes features ONCE to global in both consumer
// layouts: F1[bh][s][8] f16 (K/Q fragments; per-tile kf load = 512 B fully
// coalesced) and F2[bh][9][s] f16 (V^T, key-index bits 2<->3 permutation
// PRE-BAKED into s, row 8 = ones for the denominator). attn then has NO LDS,
// NO barriers, NO chunk loop: free-running waves stream 64 K-tiles from
// L2/L3-resident F (8.5 MB total) with 2-deep register prefetch.
//
// Layouts (HW-verified, unchanged): S^T = mfma_32x32x16(A=K, B=Q^T); C/D
// col=L&31, row=(reg&3)+8(reg>>2)+4(L>>5). P=exp2(S^T) packs with pkrtz in
// natural reg order into the PV B-frag given the baked V^T key permutation.
// qf=0 on half1 kills k=8..15 padding. Ones-row 8 of F2 gives the softmax
// denominator; PV out rows 9..31 (lanes ln>8 clamp to ones-row) are garbage
// never stored. Plain-exp softmax exact: |score*log2e/sqrt8| <= 4.1.
// ---------------------------------------------------------------------------

__launch_bounds__(256, 4)
__global__ void feat_kernel(const float* __restrict__ x,
                            const float* __restrict__ theta,
                            _Float16* __restrict__ F1,
                            _Float16* __restrict__ F2) {
  const int tid = threadIdx.x;
  const int bh  = blockIdx.x >> 3;          // 64 (b,h)
  const int s   = ((blockIdx.x & 7) << 8) + tid;
  const int b = bh >> 4, h = bh & 15;

  float th[8];
#pragma unroll
  for (int i = 0; i < 8; ++i) th[i] = theta[i];

  const float* xp = x + ((size_t)b * SEQ + s) * EMB + h * DK;
  const float4 a = *(const float4*)(xp);
  const float4 c = *(const float4*)(xp + 4);
  float r[8];
  r[0] = __cosf(a.x + th[0]);
  r[1] = r[0] * __cosf(a.y + th[1]);
  r[2] = r[1] * __cosf(a.z + th[2]);
  r[3] = r[2] * __cosf(a.w + th[3]);
  r[4] = r[3] * __cosf(c.x + th[4]);
  r[5] = r[4] * __cosf(c.y + th[5]);
  r[6] = r[5] * __cosf(c.z + th[6]);
  r[7] = r[6] * __cosf(c.w + th[7]);

  _Float16 hv[8];
#pragma unroll
  for (int i = 0; i < 8; ++i) hv[i] = (_Float16)r[i];

  // F1[bh][s][8]: 16 B contiguous store, s-consecutive lanes => coalesced
  union { v4h v[2]; float4 f; } u;
  u.v[0] = (v4h){hv[0], hv[1], hv[2], hv[3]};
  u.v[1] = (v4h){hv[4], hv[5], hv[6], hv[7]};
  *(float4*)(F1 + ((size_t)bh * SEQ + s) * 8) = u.f;

  // F2[bh][d][s_perm]: key-index bits 2<->3 swap baked in; per-d stores are
  // s-coalesced (permutation stays within each 16-group / 32 B)
  const int sp = (s & ~15) | (s & 3) | ((s & 4) << 1) | ((s & 8) >> 1);
  _Float16* f2 = F2 + (size_t)bh * 9 * SEQ;
#pragma unroll
  for (int d = 0; d < 8; ++d) f2[(size_t)d * SEQ + sp] = hv[d];
  f2[(size_t)8 * SEQ + s] = (_Float16)1.0f;   // denominator ones-row
}

__launch_bounds__(256, 4)
__global__ void attn_kernel(const _Float16* __restrict__ F1,
                            const _Float16* __restrict__ F2,
                            _Float16* __restrict__ Ah /* [B*S][128] f16 */) {
  const int tid = threadIdx.x;
  const int L   = tid & 63;
  const int ln  = L & 31;
  const int hf  = L >> 5;                 // lane half
  const int wv  = tid >> 6;               // wave 0..3 (free-running, no barriers)
  const int bh  = blockIdx.x >> 4;
  const int qt  = (blockIdx.x & 15) * 4 + wv;   // wave's 32-row q tile (0..63)
  const int qb  = qt * 32;
  const int b = bh >> 4, h = bh & 15;
  const int mrow = (ln < 8) ? ln : 8;     // V^T row; ln>=8 -> ones-row 8

  const _Float16* f1 = F1 + (size_t)bh * SEQ * 8;
  const _Float16* kp = f1 + ln * 8;                                // K rows
  const _Float16* vp = F2 + (size_t)bh * 9 * SEQ + (size_t)mrow * SEQ + hf * 8;

  // qf: coalesced 16 B load of this wave's q rows; half1 stays 0
  v8h qf = {0, 0, 0, 0, 0, 0, 0, 0};
  if (hf == 0) {
    const v8h qv = *(const v8h*)(f1 + (size_t)(qb + ln) * 8);
    const _Float16 qs = (_Float16)QSCALE;
    const v8h qsc = {qs, qs, qs, qs, qs, qs, qs, qs};
    qf = qv * qsc;
  }

  v16f acc;
#pragma unroll
  for (int i = 0; i < 16; ++i) acc[i] = 0.f;
  v16f zf;
#pragma unroll
  for (int i = 0; i < 16; ++i) zf[i] = 0.f;

  // ---- prologue: K(0), K(1), vt(0); S(0) ----
  v8h kf0  = *(const v8h*)kp; kp += 256;          // K-tile 0 (32 rows x 16 B)
  v8h kf_n = *(const v8h*)kp; kp += 256;          // K-tile 1
  v8h vt0_c = *(const v8h*)(vp);
  v8h vt1_c = *(const v8h*)(vp + 16); vp += 32;   // vt tile 0
  v16f s_cur = __builtin_amdgcn_mfma_f32_32x32x16_f16(kf0, qf, zf, 0, 0, 0);

  // ---- 64 K-tiles, phase-free, 2-deep prefetch ----
  // state entering iter kb: s_cur=S(kb); kf_n=K(kb+1) (loaded iter kb-1);
  // vt_c=vt(kb) (loaded iter kb-1). kf_f read at kb=62 touches the 512-elem
  // pad after F1 (harmless, never used in an MFMA that matters... it IS
  // mfma'd at kb=62->s_next=S(63)? no: kf_f(62)=row 2048 tile becomes kf_n
  // and is never consumed; S(63) uses kf_n loaded at kb=61).
#pragma unroll 4
  for (int kb = 0; kb < 63; ++kb) {
    const v8h kf_f = *(const v8h*)kp; kp += 256;        // K(kb+2)
    const v16f s_next = __builtin_amdgcn_mfma_f32_32x32x16_f16(kf_n, qf, zf, 0, 0, 0);
    const v8h vt0_n = *(const v8h*)(vp);
    const v8h vt1_n = *(const v8h*)(vp + 16); vp += 32; // vt(kb+1)
    union { v2fp p[4]; v8h v; } p0, p1;
#pragma unroll
    for (int i = 0; i < 4; ++i) {
      p0.p[i] = __builtin_amdgcn_cvt_pkrtz(
          __builtin_amdgcn_exp2f(s_cur[2 * i]),
          __builtin_amdgcn_exp2f(s_cur[2 * i + 1]));
    }
    acc = __builtin_amdgcn_mfma_f32_32x32x16_f16(vt0_c, p0.v, acc, 0, 0, 0);
#pragma unroll
    for (int i = 0; i < 4; ++i) {
      p1.p[i] = __builtin_amdgcn_cvt_pkrtz(
          __builtin_amdgcn_exp2f(s_cur[8 + 2 * i]),
          __builtin_amdgcn_exp2f(s_cur[8 + 2 * i + 1]));
    }
    acc = __builtin_amdgcn_mfma_f32_32x32x16_f16(vt1_c, p1.v, acc, 0, 0, 0);
    s_cur = s_next; kf_n = kf_f; vt0_c = vt0_n; vt1_c = vt1_n;
  }
  // peeled kb=63: consume s_cur, no loads
  {
    union { v2fp p[4]; v8h v; } p0, p1;
#pragma unroll
    for (int i = 0; i < 4; ++i) {
      p0.p[i] = __builtin_amdgcn_cvt_pkrtz(
          __builtin_amdgcn_exp2f(s_cur[2 * i]),
          __builtin_amdgcn_exp2f(s_cur[2 * i + 1]));
      p1.p[i] = __builtin_amdgcn_cvt_pkrtz(
          __builtin_amdgcn_exp2f(s_cur[8 + 2 * i]),
          __builtin_amdgcn_exp2f(s_cur[8 + 2 * i + 1]));
    }
    acc = __builtin_amdgcn_mfma_f32_32x32x16_f16(vt0_c, p0.v, acc, 0, 0, 0);
    acc = __builtin_amdgcn_mfma_f32_32x32x16_f16(vt1_c, p1.v, acc, 0, 0, 0);
  }

  // ---- epilogue ----
  // acc C-layout: col=q=L&31, row=(reg&3)+8(reg>>2)+4*hf.
  // half0 regs 0-3 = dims 0-3, reg4 = row 8 = den; half1 regs 0-3 = dims 4-7.
  {
    const float den = __shfl(acc[4], ln, 64);   // from half0 lane ln
    const float inv = 1.0f / den;
    const int qrow = qb + ln;
    v4h o = {(_Float16)(acc[0] * inv), (_Float16)(acc[1] * inv),
             (_Float16)(acc[2] * inv), (_Float16)(acc[3] * inv)};
    *(v4h*)(Ah + ((size_t)b * SEQ + qrow) * EMB + h * DK + hf * 4) = o;
  }
}

// ---------------------------------------------------------------------------
// MFMA projection (unchanged from R10-R15). out = Ah · W^T, fp32 out.
// W converted f32->f16 during LDS staging; W row-major IS the B-fragment
// source. Block: 64 rows x 64 cols (grid 128x2), LDS 35 KB, 4 blocks/CU.
// ---------------------------------------------------------------------------
__launch_bounds__(256, 4)
__global__ void proj_kernel(const _Float16* __restrict__ Ah,
                            const float* __restrict__ W,
                            float* __restrict__ out) {
  __shared__ __align__(16) _Float16 Ahs[64][136];
  __shared__ __align__(16) _Float16 Whs[64][136];

  const int tid  = threadIdx.x;
  const int L    = tid & 63;
  const int wv   = tid >> 6;
  const int quad = L >> 4;
  const int ln   = L & 15;
  const int rowbase = blockIdx.x * 64;
  const int colbase = blockIdx.y * 64;

#pragma unroll
  for (int it = 0; it < 4; ++it) {
    const int idx = it * 256 + tid;
    const int r  = idx >> 4;
    const int c8 = idx & 15;
    *(uint4*)&Ahs[r][c8 * 8] =
        *(const uint4*)(Ah + (size_t)(rowbase + r) * EMB + c8 * 8);
  }
#pragma unroll
  for (int it = 0; it < 8; ++it) {
    const int idx = it * 256 + tid;
    const int n  = idx >> 5;
    const int c4 = idx & 31;
    const float4 w = *(const float4*)(W + (size_t)(colbase + n) * EMB + c4 * 4);
    v4h wh = {(_Float16)w.x, (_Float16)w.y, (_Float16)w.z, (_Float16)w.w};
    *(v4h*)&Whs[n][c4 * 4] = wh;
  }
  __syncthreads();

  v4f acc[4];
#pragma unroll
  for (int nt = 0; nt < 4; ++nt) acc[nt] = (v4f){0.f, 0.f, 0.f, 0.f};

#pragma unroll
  for (int k8 = 0; k8 < 8; ++k8) {
    const v4h af = *(const v4h*)&Ahs[wv * 16 + ln][k8 * 16 + quad * 4];
#pragma unroll
    for (int nt = 0; nt < 4; ++nt) {
      const v4h bf = *(const v4h*)&Whs[nt * 16 + ln][k8 * 16 + quad * 4];
      acc[nt] = __builtin_amdgcn_mfma_f32_16x16x16f16(af, bf, acc[nt], 0, 0, 0);
    }
  }

#pragma unroll
  for (int nt = 0; nt < 4; ++nt) {
    const int col = colbase + nt * 16 + ln;
#pragma unroll
    for (int r = 0; r < 4; ++r) {
      out[(size_t)(rowbase + wv * 16 + quad * 4 + r) * EMB + col] = acc[nt][r];
    }
  }
}

// ---------------------------------------------------------------------------
extern "C" void kernel_launch(void* const* d_in, const int* in_sizes, int n_in,
                              void* d_out, int out_size, void* d_ws, size_t ws_size,
                              hipStream_t stream) {
  const float* x     = (const float*)d_in[0];  // [4,2048,128]
  const float* theta = (const float*)d_in[1];  // [8]
  const float* w_out = (const float*)d_in[2];  // [128,128]
  float* out = (float*)d_out;                  // [4,2048,128]

  // workspace: Ah [8192][128] f16 (2 MB) | F1 [64][2048][8] f16 + 512 pad
  // (2 MB) | F2 [64][9][2048] f16 (2.25 MB)
  _Float16* Ah = (_Float16*)d_ws;
  _Float16* F1 = Ah + (size_t)BATCH * SEQ * EMB;
  _Float16* F2 = F1 + (size_t)64 * SEQ * 8 + 512;

  // features once, both layouts: 64 bh x 8 s-chunks = 512 blocks
  feat_kernel<<<dim3(512), dim3(256), 0, stream>>>(x, theta, F1, F2);

  // phase-free attention: 64 bh x 16 = 1024 blocks, 4 free-running waves
  attn_kernel<<<dim3(1024), dim3(256), 0, stream>>>(F1, F2, Ah);

  // projection: 128 row-tiles x 2 col-tiles
  proj_kernel<<<dim3((BATCH * SEQ) / 64, 2), dim3(256), 0, stream>>>(Ah, w_out, out);
}

// Round 5
// 95.795 us; speedup vs baseline: 1.0499x; 1.0499x over previous
//
#include <hip/hip_runtime.h>

#define BATCH 4
#define SEQ   2048
#define EMB   128
#define NH    16
#define DK    8

// log2(e) / sqrt(8): fold softmax temperature into exp2 (pre-multiplied into qf)
#define QSCALE 0.510069726f

typedef _Float16 v4h  __attribute__((ext_vector_type(4)));
typedef _Float16 v8h  __attribute__((ext_vector_type(8)));
typedef __fp16   v2fp __attribute__((ext_vector_type(2)));
typedef float    v4f  __attribute__((ext_vector_type(4)));
typedef float    v16f __attribute__((ext_vector_type(16)));

// ---------------------------------------------------------------------------
// R20: dual-q per wave (issue-count reduction). Ledger: R16 2x-waves flat,
// R17 exp->VALU -18us, R18 S-skew flat, R19 phase-free flat; wall tracks
// added VALU 1:1 (R17). Model: SIMD issue port is the saturated resource
// (exp@~8cyc x16 + pkrtz x8 + overhead ~= VALUBusy 53% of slot; + MFMA/load
// issue ~= full). Only lever: fewer issue cycles per score. Here each wave
// runs TWO independent q-chains (2 q-tiles) against HALF the keys, sharing
// kf load, vt loads, addressing and loop control across both chains; the
// sibling chain also fills each chain's S-MFMA/exp latency. In-block key
// split: waves (2p, 2p+1) cover key halves 0/1 for q-tiles {2p, 2p+1};
// plain-exp partials are additive (R16-verified), combined via 10 KB LDS
// in the epilogue. Grid/occupancy unchanged (1024 blocks, 4 waves).
//
// Layouts (HW-verified, unchanged): S^T = mfma_32x32x16(A=K, B=Q^T); C/D
// col=L&31, row=(reg&3)+8(reg>>2)+4(L>>5). P=exp2(S^T) packs with pkrtz in
// natural reg order into the PV B-frag given the baked V^T key permutation
// (bits 2<->3 of key index, pre-baked in F2 by feat_kernel). qf=0 on half1
// kills k=8..15 padding. Ones-row 8 of F2 = softmax denominator; PV rows
// 9..31 garbage never stored. |score*log2e/sqrt8| <= 4.1 so plain exp exact.
// ---------------------------------------------------------------------------

__launch_bounds__(256, 4)
__global__ void feat_kernel(const float* __restrict__ x,
                            const float* __restrict__ theta,
                            _Float16* __restrict__ F1,
                            _Float16* __restrict__ F2) {
  const int tid = threadIdx.x;
  const int bh  = blockIdx.x >> 3;          // 64 (b,h)
  const int s   = ((blockIdx.x & 7) << 8) + tid;
  const int b = bh >> 4, h = bh & 15;

  float th[8];
#pragma unroll
  for (int i = 0; i < 8; ++i) th[i] = theta[i];

  const float* xp = x + ((size_t)b * SEQ + s) * EMB + h * DK;
  const float4 a = *(const float4*)(xp);
  const float4 c = *(const float4*)(xp + 4);
  float r[8];
  r[0] = __cosf(a.x + th[0]);
  r[1] = r[0] * __cosf(a.y + th[1]);
  r[2] = r[1] * __cosf(a.z + th[2]);
  r[3] = r[2] * __cosf(a.w + th[3]);
  r[4] = r[3] * __cosf(c.x + th[4]);
  r[5] = r[4] * __cosf(c.y + th[5]);
  r[6] = r[5] * __cosf(c.z + th[6]);
  r[7] = r[6] * __cosf(c.w + th[7]);

  _Float16 hv[8];
#pragma unroll
  for (int i = 0; i < 8; ++i) hv[i] = (_Float16)r[i];

  // F1[bh][s][8]: 16 B contiguous store, s-consecutive lanes => coalesced
  union { v4h v[2]; float4 f; } u;
  u.v[0] = (v4h){hv[0], hv[1], hv[2], hv[3]};
  u.v[1] = (v4h){hv[4], hv[5], hv[6], hv[7]};
  *(float4*)(F1 + ((size_t)bh * SEQ + s) * 8) = u.f;

  // F2[bh][d][s_perm]: key-index bits 2<->3 swap baked in; per-d stores are
  // s-coalesced (permutation stays within each 16-group / 32 B)
  const int sp = (s & ~15) | (s & 3) | ((s & 4) << 1) | ((s & 8) >> 1);
  _Float16* f2 = F2 + (size_t)bh * 9 * SEQ;
#pragma unroll
  for (int d = 0; d < 8; ++d) f2[(size_t)d * SEQ + sp] = hv[d];
  f2[(size_t)8 * SEQ + s] = (_Float16)1.0f;   // denominator ones-row
}

__launch_bounds__(256, 4)
__global__ void attn_kernel(const _Float16* __restrict__ F1,
                            const _Float16* __restrict__ F2,
                            _Float16* __restrict__ Ah /* [B*S][128] f16 */) {
  __shared__ float P[4][2][5][64];          // 10 KB partial-combine buffer

  const int tid = threadIdx.x;
  const int L   = tid & 63;
  const int ln  = L & 31;
  const int hf  = L >> 5;                   // lane half
  const int wv  = tid >> 6;                 // wave 0..3
  const int pr  = wv >> 1;                  // q-pair 0..1
  const int kh  = wv & 1;                   // key half
  const int bh  = blockIdx.x >> 4;
  const int qbase = (blockIdx.x & 15) * 128;
  const int b = bh >> 4, h = bh & 15;
  const int mrow = (ln < 8) ? ln : 8;       // V^T row; ln>=8 -> ones-row 8

  const _Float16* f1 = F1 + (size_t)bh * SEQ * 8;
  const _Float16* kp = f1 + (size_t)(kh * 1024 + ln) * 8;   // this half's K rows
  const _Float16* vp = F2 + (size_t)bh * 9 * SEQ + (size_t)mrow * SEQ
                          + kh * 1024 + hf * 8;

  // two q-fragments (q-tiles 2*pr and 2*pr+1); half1 stays 0
  v8h qf0 = {0, 0, 0, 0, 0, 0, 0, 0};
  v8h qf1 = {0, 0, 0, 0, 0, 0, 0, 0};
  if (hf == 0) {
    const _Float16 qs = (_Float16)QSCALE;
    const v8h qsc = {qs, qs, qs, qs, qs, qs, qs, qs};
    qf0 = *(const v8h*)(f1 + (size_t)(qbase + pr * 64 + ln) * 8) * qsc;
    qf1 = *(const v8h*)(f1 + (size_t)(qbase + pr * 64 + 32 + ln) * 8) * qsc;
  }

  v16f acc0, acc1, zf;
#pragma unroll
  for (int i = 0; i < 16; ++i) { acc0[i] = 0.f; acc1[i] = 0.f; zf[i] = 0.f; }

  // ---- 32 K-tiles, dual chain, kf 1-deep prefetch ----
  v8h kf = *(const v8h*)kp; kp += 256;
#pragma unroll 4
  for (int kb = 0; kb < 32; ++kb) {
    const v8h kf_n = *(const v8h*)kp; kp += 256;   // next tile (pad-safe at end)
    const v16f s0 = __builtin_amdgcn_mfma_f32_32x32x16_f16(kf, qf0, zf, 0, 0, 0);
    const v16f s1 = __builtin_amdgcn_mfma_f32_32x32x16_f16(kf, qf1, zf, 0, 0, 0);
    const v8h vt0 = *(const v8h*)(vp);
    const v8h vt1 = *(const v8h*)(vp + 16); vp += 32;
    union { v2fp p[4]; v8h v; } a0, a1, b0, b1;
#pragma unroll
    for (int i = 0; i < 4; ++i) {
      a0.p[i] = __builtin_amdgcn_cvt_pkrtz(
          __builtin_amdgcn_exp2f(s0[2 * i]),
          __builtin_amdgcn_exp2f(s0[2 * i + 1]));
      a1.p[i] = __builtin_amdgcn_cvt_pkrtz(
          __builtin_amdgcn_exp2f(s0[8 + 2 * i]),
          __builtin_amdgcn_exp2f(s0[8 + 2 * i + 1]));
    }
    acc0 = __builtin_amdgcn_mfma_f32_32x32x16_f16(vt0, a0.v, acc0, 0, 0, 0);
    acc0 = __builtin_amdgcn_mfma_f32_32x32x16_f16(vt1, a1.v, acc0, 0, 0, 0);
#pragma unroll
    for (int i = 0; i < 4; ++i) {
      b0.p[i] = __builtin_amdgcn_cvt_pkrtz(
          __builtin_amdgcn_exp2f(s1[2 * i]),
          __builtin_amdgcn_exp2f(s1[2 * i + 1]));
      b1.p[i] = __builtin_amdgcn_cvt_pkrtz(
          __builtin_amdgcn_exp2f(s1[8 + 2 * i]),
          __builtin_amdgcn_exp2f(s1[8 + 2 * i + 1]));
    }
    acc1 = __builtin_amdgcn_mfma_f32_32x32x16_f16(vt0, b0.v, acc1, 0, 0, 0);
    acc1 = __builtin_amdgcn_mfma_f32_32x32x16_f16(vt1, b1.v, acc1, 0, 0, 0);
    kf = kf_n;
  }

  // ---- epilogue: combine key-half partials across the wave pair ----
  // acc C-layout: col=q=L&31, row=(reg&3)+8(reg>>2)+4*hf.
  // half0 regs 0-3 = dims 0-3, reg4 = row 8 = den; half1 regs 0-3 = dims 4-7.
#pragma unroll
  for (int r = 0; r < 5; ++r) {
    P[wv][0][r][L] = acc0[r];
    P[wv][1][r][L] = acc1[r];
  }
  __syncthreads();
  {
    const int p2 = (wv >> 1) << 1;      // pair base wave
    const int c  = wv & 1;              // this wave stores chain c => qtile wv
    float sum[4];
#pragma unroll
    for (int r = 0; r < 4; ++r) sum[r] = P[p2][c][r][L] + P[p2 + 1][c][r][L];
    const float den = P[p2][c][4][ln] + P[p2 + 1][c][4][ln];
    const float inv = 1.0f / den;
    const int qrow = qbase + wv * 32 + ln;
    v4h o = {(_Float16)(sum[0] * inv), (_Float16)(sum[1] * inv),
             (_Float16)(sum[2] * inv), (_Float16)(sum[3] * inv)};
    *(v4h*)(Ah + ((size_t)b * SEQ + qrow) * EMB + h * DK + hf * 4) = o;
  }
}

// ---------------------------------------------------------------------------
// MFMA projection (unchanged). out = Ah · W^T, fp32 out. W converted f32->f16
// during LDS staging; W row-major IS the B-fragment source. Block: 64 rows x
// 64 cols (grid 128x2), LDS 35 KB, 4 blocks/CU.
// ---------------------------------------------------------------------------
__launch_bounds__(256, 4)
__global__ void proj_kernel(const _Float16* __restrict__ Ah,
                            const float* __restrict__ W,
                            float* __restrict__ out) {
  __shared__ __align__(16) _Float16 Ahs[64][136];
  __shared__ __align__(16) _Float16 Whs[64][136];

  const int tid  = threadIdx.x;
  const int L    = tid & 63;
  const int wv   = tid >> 6;
  const int quad = L >> 4;
  const int ln   = L & 15;
  const int rowbase = blockIdx.x * 64;
  const int colbase = blockIdx.y * 64;

#pragma unroll
  for (int it = 0; it < 4; ++it) {
    const int idx = it * 256 + tid;
    const int r  = idx >> 4;
    const int c8 = idx & 15;
    *(uint4*)&Ahs[r][c8 * 8] =
        *(const uint4*)(Ah + (size_t)(rowbase + r) * EMB + c8 * 8);
  }
#pragma unroll
  for (int it = 0; it < 8; ++it) {
    const int idx = it * 256 + tid;
    const int n  = idx >> 5;
    const int c4 = idx & 31;
    const float4 w = *(const float4*)(W + (size_t)(colbase + n) * EMB + c4 * 4);
    v4h wh = {(_Float16)w.x, (_Float16)w.y, (_Float16)w.z, (_Float16)w.w};
    *(v4h*)&Whs[n][c4 * 4] = wh;
  }
  __syncthreads();

  v4f acc[4];
#pragma unroll
  for (int nt = 0; nt < 4; ++nt) acc[nt] = (v4f){0.f, 0.f, 0.f, 0.f};

#pragma unroll
  for (int k8 = 0; k8 < 8; ++k8) {
    const v4h af = *(const v4h*)&Ahs[wv * 16 + ln][k8 * 16 + quad * 4];
#pragma unroll
    for (int nt = 0; nt < 4; ++nt) {
      const v4h bf = *(const v4h*)&Whs[nt * 16 + ln][k8 * 16 + quad * 4];
      acc[nt] = __builtin_amdgcn_mfma_f32_16x16x16f16(af, bf, acc[nt], 0, 0, 0);
    }
  }

#pragma unroll
  for (int nt = 0; nt < 4; ++nt) {
    const int col = colbase + nt * 16 + ln;
#pragma unroll
    for (int r = 0; r < 4; ++r) {
      out[(size_t)(rowbase + wv * 16 + quad * 4 + r) * EMB + col] = acc[nt][r];
    }
  }
}

// ---------------------------------------------------------------------------
extern "C" void kernel_launch(void* const* d_in, const int* in_sizes, int n_in,
                              void* d_out, int out_size, void* d_ws, size_t ws_size,
                              hipStream_t stream) {
  const float* x     = (const float*)d_in[0];  // [4,2048,128]
  const float* theta = (const float*)d_in[1];  // [8]
  const float* w_out = (const float*)d_in[2];  // [128,128]
  float* out = (float*)d_out;                  // [4,2048,128]

  // workspace: Ah [8192][128] f16 (2 MB) | F1 [64][2048][8] f16 + 512-f16 pad
  // (kf prefetch overruns 1 tile = 512 B at the last iter) | F2 [64][9][2048]
  _Float16* Ah = (_Float16*)d_ws;
  _Float16* F1 = Ah + (size_t)BATCH * SEQ * EMB;
  _Float16* F2 = F1 + (size_t)64 * SEQ * 8 + 512;

  // features once, both layouts: 64 bh x 8 s-chunks = 512 blocks
  feat_kernel<<<dim3(512), dim3(256), 0, stream>>>(x, theta, F1, F2);

  // dual-q attention: 64 bh x 16 q-blocks = 1024 blocks, 4 waves
  attn_kernel<<<dim3(1024), dim3(256), 0, stream>>>(F1, F2, Ah);

  // projection: 128 row-tiles x 2 col-tiles
  proj_kernel<<<dim3((BATCH * SEQ) / 64, 2), dim3(256), 0, stream>>>(Ah, w_out, out);
}